// Round 2
// baseline (372.260 us; speedup 1.0000x reference)
//
#include <hip/hip_runtime.h>

// out[1,8192] = x[1,8192] @ W[8192,8192] + b[8192]   (all fp32)
// Memory-bound: stream W (256 MiB) once. Split-K into 128 chunks for
// occupancy (1024 blocks = 4/CU, 16 waves/CU), partials to d_ws (4 MB,
// no atomics), then a small LDS-tree reduction kernel adds bias.

#define IN_LEN   8192
#define OUT_LEN  8192
#define SPLITS   128
#define K_CHUNK  (IN_LEN / SPLITS)     // 64
#define THREADS  256
#define NCOL4    (OUT_LEN / 4)         // 2048 float4 columns

__global__ __launch_bounds__(THREADS, 4)
void matvec_stage1(const float* __restrict__ x,
                   const float* __restrict__ W,
                   float* __restrict__ ws) {
    const int col4  = blockIdx.x * THREADS + threadIdx.x;  // float4 column
    const int kbase = blockIdx.y * K_CHUNK;

    const float4* __restrict__ W4 = (const float4*)W;
    float4 acc = make_float4(0.f, 0.f, 0.f, 0.f);

#pragma unroll 16
    for (int i = 0; i < K_CHUNK; ++i) {
        const float  xs = x[kbase + i];                    // wave-uniform -> s_load
        const float4 w  = W4[(size_t)(kbase + i) * NCOL4 + col4];
        acc.x += xs * w.x;
        acc.y += xs * w.y;
        acc.z += xs * w.z;
        acc.w += xs * w.w;
    }

    // partial layout: ws[split][OUT_LEN], coalesced float4 store
    ((float4*)ws)[(size_t)blockIdx.y * NCOL4 + col4] = acc;
}

// Reduce SPLITS partials per column + bias. Block covers 64 columns with
// 4 wave-rows of the split dimension, LDS tree at the end.
__global__ __launch_bounds__(THREADS)
void matvec_stage2(const float* __restrict__ ws,
                   const float* __restrict__ b,
                   float* __restrict__ out) {
    const int c   = threadIdx.x & 63;        // column within block
    const int g   = threadIdx.x >> 6;        // split-group 0..3
    const int col = blockIdx.x * 64 + c;

    float s = 0.f;
#pragma unroll 8
    for (int sp = g; sp < SPLITS; sp += 4)   // lanes read consecutive cols: coalesced
        s += ws[(size_t)sp * OUT_LEN + col];

    __shared__ float red[4][64];
    red[g][c] = s;
    __syncthreads();

    if (threadIdx.x < 64) {
        const int j = blockIdx.x * 64 + threadIdx.x;
        out[j] = red[0][threadIdx.x] + red[1][threadIdx.x] +
                 red[2][threadIdx.x] + red[3][threadIdx.x] + b[j];
    }
}

extern "C" void kernel_launch(void* const* d_in, const int* in_sizes, int n_in,
                              void* d_out, int out_size, void* d_ws, size_t ws_size,
                              hipStream_t stream) {
    const float* x = (const float*)d_in[0];   // (1, 8192)
    const float* W = (const float*)d_in[1];   // (8192, 8192) row-major
    const float* b = (const float*)d_in[2];   // (8192,)
    float* out = (float*)d_out;               // (1, 8192)
    float* ws  = (float*)d_ws;                // >= SPLITS*OUT_LEN*4 = 4 MB

    dim3 grid1(NCOL4 / THREADS, SPLITS);      // (8, 128) = 1024 blocks
    matvec_stage1<<<grid1, dim3(THREADS), 0, stream>>>(x, W, ws);

    matvec_stage2<<<dim3(OUT_LEN / 64), dim3(THREADS), 0, stream>>>(ws, b, out);
}